// Round 13
// baseline (569.161 us; speedup 1.0000x reference)
//
#include <hip/hip_runtime.h>
#include <cmath>

// N=50000 nodes, E=800000 edges, B=64 graphs, H=2 heads, D=128, FIN=128, L=2.

typedef __attribute__((ext_vector_type(8))) short short8v;   // 8 x bf16 (4 VGPRs)
typedef __attribute__((ext_vector_type(4))) float float4v;   // MFMA acc
typedef __attribute__((ext_vector_type(2))) float float2v;   // packed f32 pair

__device__ __forceinline__ float sigmoidf_(float x){ return 1.f/(1.f+expf(-x)); }

__device__ __forceinline__ unsigned f2bf_rne(float f){
  unsigned u = __float_as_uint(f);
  return (u + 0x7fffu + ((u >> 16) & 1u)) >> 16;   // round-nearest-even bf16
}
__device__ __forceinline__ float bf2f(ushort v){ return __uint_as_float((unsigned)v << 16); }
// fp8 e4m3 (hardware cvt, OCP on gfx950; encode+decode use the same HW format)
__device__ __forceinline__ unsigned char f2fp8(float f){
  unsigned v = __builtin_amdgcn_cvt_pk_fp8_f32(f, f, 0, false);
  return (unsigned char)(v & 0xffu);
}

// ---------------- CSR build (by dst) ----------------
__global__ void k_hist(const int* __restrict__ dst, int* __restrict__ deg, int E){
  int e = blockIdx.x*blockDim.x + threadIdx.x;
  if (e < E) atomicAdd(&deg[dst[e]], 1);
}

// parallel exclusive scan: chunk sums -> tiny scan -> apply
#define CHUNK 1024
__global__ __launch_bounds__(256) void k_chunksum(const int* __restrict__ in, int* __restrict__ csum, int n){
  int b = blockIdx.x;
  int tid = threadIdx.x;
  int v = 0;
  #pragma unroll
  for (int k = 0; k < 4; k++){
    int i = b*CHUNK + tid + k*256;
    if (i < n) v += in[i];
  }
  for (int d = 1; d < 64; d <<= 1) v += __shfl_xor(v, d);
  __shared__ int ws[4];
  if ((tid & 63) == 0) ws[tid>>6] = v;
  __syncthreads();
  if (tid == 0) csum[b] = ws[0]+ws[1]+ws[2]+ws[3];
}

__global__ void k_scan_small(const int* __restrict__ csum, int* __restrict__ cpre, int nb,
                             int* __restrict__ total_out){
  int lane = threadIdx.x;  // 64 threads, nb <= 64
  int v = (lane < nb) ? csum[lane] : 0;
  int incl = v;
  for (int d = 1; d < 64; d <<= 1){ int t = __shfl_up(incl, d); if (lane >= d) incl += t; }
  if (lane < nb) cpre[lane] = incl - v;
  if (lane == 63) *total_out = incl;
}

__global__ __launch_bounds__(256) void k_scan_apply(const int* __restrict__ in, const int* __restrict__ cpre,
                                                    int* __restrict__ offs, int n){
  int b = blockIdx.x;
  int tid = threadIdx.x, lane = tid & 63, wid = tid >> 6;
  int x[4];
  int s = 0;
  #pragma unroll
  for (int k = 0; k < 4; k++){
    int i = b*CHUNK + tid*4 + k;
    x[k] = (i < n) ? in[i] : 0;
    s += x[k];
  }
  int incl = s;
  for (int d = 1; d < 64; d <<= 1){ int t = __shfl_up(incl, d); if (lane >= d) incl += t; }
  __shared__ int ws[4];
  if (lane == 63) ws[wid] = incl;
  __syncthreads();
  int wpre = 0;
  for (int w = 0; w < wid; w++) wpre += ws[w];
  int base = cpre[b] + wpre + incl - s;
  #pragma unroll
  for (int k = 0; k < 4; k++){
    int i = b*CHUNK + tid*4 + k;
    if (i < n) offs[i] = base;
    base += x[k];
  }
}

// scatter src ids into CSR slot order (layer-invariant, built once)
__global__ void k_scatter_src(const int* __restrict__ src, const int* __restrict__ dst,
                              const int* __restrict__ offs, int* __restrict__ cnt,
                              int* __restrict__ srcP, int E){
  int e = blockIdx.x*blockDim.x + threadIdx.x;
  if (e < E){ int d = dst[e]; int p = atomicAdd(&cnt[d], 1); srcP[offs[d] + p] = src[e]; }
}

__global__ void k_graph_bounds(const int* __restrict__ ng, int* __restrict__ gstart, int n, int nb){
  int i = blockIdx.x*blockDim.x + threadIdx.x;
  if (i >= n) return;
  int g = ng[i];
  int gp = (i == 0) ? -1 : ng[i-1];
  for (int b = gp+1; b <= g; b++) gstart[b] = i;
  if (i == n-1) for (int b = g+1; b <= nb; b++) gstart[b] = n;
}

// ---------------- fused nfeats->bf16 + layer-0 pool gate (wave per node) ----------------
__global__ __launch_bounds__(256) void k_tobf16_gate(const float* __restrict__ in,
    const float* __restrict__ gw, const float* __restrict__ gb,
    ushort* __restrict__ out, float* __restrict__ gate, int Nn){
  int n = blockIdx.x*4 + (threadIdx.x >> 6);
  if (n >= Nn) return;
  int lane = threadIdx.x & 63;
  float2 v = *(const float2*)(in + (size_t)n*128 + lane*2);
  unsigned pk = (f2bf_rne(v.y) << 16) | f2bf_rne(v.x);
  *(unsigned*)(out + (size_t)n*128 + lane*2) = pk;
  float2 gv = *(const float2*)(gw + lane*2);
  float p = v.x*gv.x + v.y*gv.y;
  for (int k = 1; k < 64; k <<= 1) p += __shfl_xor(p, k);
  if (lane == 0) gate[n] = p + gb[0];
}

// W [128,256] f32 -> Wt [256,128] bf16
__global__ void k_wt(const float* __restrict__ W, ushort* __restrict__ Wt, int total){
  int idx = blockIdx.x*blockDim.x + threadIdx.x;
  if (idx >= total) return;
  int c = idx >> 7;
  int k = idx & 127;
  Wt[idx] = (ushort)f2bf_rne(W[(size_t)k*256 + c]);
}

// LSTM weight prep: packed bf16 pairs.
__global__ void k_lstm_prep(const float* __restrict__ Wih, const float* __restrict__ Whh,
                            const float* __restrict__ bih, const float* __restrict__ bhh,
                            unsigned* __restrict__ Wxp, unsigned* __restrict__ Whp,
                            float* __restrict__ bias2){
  int idx = blockIdx.x*blockDim.x + threadIdx.x;   // 2*2*64*512 = 131072
  if (idx >= 131072) return;
  int j   = idx & 511;
  int c   = (idx >> 9) & 63;
  int isH = (idx >> 15) & 1;
  int l   = idx >> 16;
  const float* srcW = isH ? Whh : Wih;
  float w0 = srcW[(size_t)l*512*128 + (size_t)j*128 + 2*c];
  float w1 = srcW[(size_t)l*512*128 + (size_t)j*128 + 2*c + 1];
  unsigned v = (f2bf_rne(w1) << 16) | f2bf_rne(w0);
  unsigned* dst = isH ? Whp : Wxp;
  dst[(size_t)l*32768 + c*512 + j] = v;
  if (!isH && c == 0) bias2[l*512 + j] = bih[l*512 + j] + bhh[l*512 + j];
}

// ---------------- MFMA GEMM (Wt staged in LDS): Y8[M,256](fp8) = Xh[M,128] @ W, fused el/er ----------------
// LDS layout [c=0..15][row=0..255][8 ushorts]: quarter-wave reads 16 contiguous rows -> conflict-free.
__global__ __launch_bounds__(256) void k_gemm_mfma(const ushort* __restrict__ Xh,
    const ushort* __restrict__ Wt, const float* __restrict__ alv, const float* __restrict__ arv,
    unsigned char* __restrict__ Y8, float* __restrict__ el, float* __restrict__ er, int M){
  __shared__ ushort WlS[16*256*8];   // 64 KB
  int tid = threadIdx.x;
  #pragma unroll
  for (int i = 0; i < 16; i++){
    int g = i*256 + tid;
    int row = g >> 4, c = g & 15;
    *(uint4*)(WlS + ((size_t)c*256 + row)*8) = *(const uint4*)(Wt + (size_t)row*128 + c*8);
  }
  __syncthreads();
  int wave = tid >> 6;
  int lane = tid & 63;
  int strip = blockIdx.x*4 + wave;
  if (strip*16 >= M) return;
  int m0 = strip*16;
  int l15 = lane & 15;
  int kg  = lane >> 4;
  int arow = m0 + l15; if (arow >= M) arow = M-1;
  short8v a[4];
  const ushort* xrow = Xh + (size_t)arow*128 + kg*8;
  #pragma unroll
  for (int ks = 0; ks < 4; ks++) a[ks] = *(const short8v*)(xrow + ks*32);
  float4v acc[16];
  #pragma unroll
  for (int nt = 0; nt < 16; nt++) acc[nt] = (float4v){0.f,0.f,0.f,0.f};
  #pragma unroll
  for (int nt = 0; nt < 16; nt++){
    #pragma unroll
    for (int ks = 0; ks < 4; ks++){
      short8v b = *(const short8v*)(WlS + (((size_t)(kg + ks*4)*256) + nt*16 + l15)*8);
      acc[nt] = __builtin_amdgcn_mfma_f32_16x16x32_bf16(a[ks], b, acc[nt], 0, 0, 0);
    }
  }
  float pel0[4]={0,0,0,0}, pel1[4]={0,0,0,0}, per0[4]={0,0,0,0}, per1[4]={0,0,0,0};
  #pragma unroll
  for (int nt = 0; nt < 16; nt++){
    int col = nt*16 + l15;
    float av = alv[col], rv = arv[col];
    #pragma unroll
    for (int j = 0; j < 4; j++){
      float v = acc[nt][j];
      int r = m0 + kg*4 + j;
      if (r < M) Y8[(size_t)r*256 + col] = f2fp8(v);
      if (nt < 8){ pel0[j] += v*av; per0[j] += v*rv; }
      else       { pel1[j] += v*av; per1[j] += v*rv; }
    }
  }
  #pragma unroll
  for (int j = 0; j < 4; j++){
    #pragma unroll
    for (int d = 1; d < 16; d <<= 1){
      pel0[j] += __shfl_xor(pel0[j], d);
      pel1[j] += __shfl_xor(pel1[j], d);
      per0[j] += __shfl_xor(per0[j], d);
      per1[j] += __shfl_xor(per1[j], d);
    }
  }
  if (l15 == 0){
    #pragma unroll
    for (int j = 0; j < 4; j++){
      int r = m0 + kg*4 + j;
      if (r < M){
        el[(size_t)r*2+0] = pel0[j];
        el[(size_t)r*2+1] = pel1[j];
        er[(size_t)r*2+0] = per0[j];
        er[(size_t)r*2+1] = per1[j];
      }
    }
  }
}

// ---------------- softmax + aggregate (in-kernel scores, fp8 gather, 8 edges/iter, 32B/lane) ----------------
// eighth = lane>>3 picks edge i+eighth; sub = lane&7 covers 32 dims of flat 256 (head = sub>>2).
#define MAXE 256
__global__ __launch_bounds__(256) void k_aggregate(const unsigned char* __restrict__ hpair8,
    const float* __restrict__ el, const float* __restrict__ er,
    const int* __restrict__ srcP, const int* __restrict__ offs,
    const float* __restrict__ bias, const float* __restrict__ gwv, const float* __restrict__ gbv,
    ushort* __restrict__ outh, float* __restrict__ gate, int Nn){
  __shared__ float sw[4][MAXE][2];   // scores -> weights (8 KB)
  __shared__ int   ss[4][MAXE];      // src ids (4 KB)
  int wave = threadIdx.x >> 6;
  int n = blockIdx.x*4 + wave;
  if (n >= Nn) return;
  int lane = threadIdx.x & 63;
  int e0 = offs[n], e1 = offs[n+1];
  int deg = e1 - e0;
  int eighth = lane >> 3;      // which edge of the 8-pack
  int sub    = lane & 7;       // 32-dim slice of flat 256
  int head   = sub >> 2;
  float2 erv = *(const float2*)(er + (size_t)n*2);
  float2v acc[16];
  #pragma unroll
  for (int k = 0; k < 16; k++) acc[k] = (float2v){0.f, 0.f};

  if (deg <= MAXE){
    float m0 = -3.4e38f, m1 = -3.4e38f;
    for (int i = lane; i < deg; i += 64){
      int s = srcP[e0 + i];
      ss[wave][i] = s;
      float2 lv = *(const float2*)(el + (size_t)s*2);
      float v0 = lv.x + erv.x, v1 = lv.y + erv.y;
      v0 = (v0 > 0.f) ? v0 : 0.2f*v0;
      v1 = (v1 > 0.f) ? v1 : 0.2f*v1;
      sw[wave][i][0] = v0; sw[wave][i][1] = v1;
      m0 = fmaxf(m0, v0); m1 = fmaxf(m1, v1);
    }
    for (int k = 1; k < 64; k <<= 1){ m0 = fmaxf(m0, __shfl_xor(m0, k)); m1 = fmaxf(m1, __shfl_xor(m1, k)); }
    float s0 = 0.f, s1 = 0.f;
    for (int i = lane; i < deg; i += 64){
      s0 += expf(sw[wave][i][0] - m0);
      s1 += expf(sw[wave][i][1] - m1);
    }
    for (int k = 1; k < 64; k <<= 1){ s0 += __shfl_xor(s0, k); s1 += __shfl_xor(s1, k); }
    float inv0 = (s0 > 0.f) ? 1.f/s0 : 0.f;
    float inv1 = (s1 > 0.f) ? 1.f/s1 : 0.f;
    for (int i = lane; i < deg; i += 64){
      sw[wave][i][0] = expf(sw[wave][i][0] - m0) * inv0;
      sw[wave][i][1] = expf(sw[wave][i][1] - m1) * inv1;
    }
    // gather (wave-internal LDS producer->consumer: no barrier needed)
    for (int i = eighth; i < deg; i += 8){
      int s = ss[wave][i];
      float w = sw[wave][i][head];
      const uint4* hp = (const uint4*)(hpair8 + (size_t)s*256 + sub*32);
      uint4 h0 = hp[0], h1 = hp[1];
      float2v wv = { w, w };
      acc[0] += wv*__builtin_amdgcn_cvt_pk_f32_fp8(h0.x, false);
      acc[1] += wv*__builtin_amdgcn_cvt_pk_f32_fp8(h0.x, true);
      acc[2] += wv*__builtin_amdgcn_cvt_pk_f32_fp8(h0.y, false);
      acc[3] += wv*__builtin_amdgcn_cvt_pk_f32_fp8(h0.y, true);
      acc[4] += wv*__builtin_amdgcn_cvt_pk_f32_fp8(h0.z, false);
      acc[5] += wv*__builtin_amdgcn_cvt_pk_f32_fp8(h0.z, true);
      acc[6] += wv*__builtin_amdgcn_cvt_pk_f32_fp8(h0.w, false);
      acc[7] += wv*__builtin_amdgcn_cvt_pk_f32_fp8(h0.w, true);
      acc[8] += wv*__builtin_amdgcn_cvt_pk_f32_fp8(h1.x, false);
      acc[9] += wv*__builtin_amdgcn_cvt_pk_f32_fp8(h1.x, true);
      acc[10]+= wv*__builtin_amdgcn_cvt_pk_f32_fp8(h1.y, false);
      acc[11]+= wv*__builtin_amdgcn_cvt_pk_f32_fp8(h1.y, true);
      acc[12]+= wv*__builtin_amdgcn_cvt_pk_f32_fp8(h1.z, false);
      acc[13]+= wv*__builtin_amdgcn_cvt_pk_f32_fp8(h1.z, true);
      acc[14]+= wv*__builtin_amdgcn_cvt_pk_f32_fp8(h1.w, false);
      acc[15]+= wv*__builtin_amdgcn_cvt_pk_f32_fp8(h1.w, true);
    }
  } else {
    // slow path (deg > MAXE): recompute per chunk
    float m0 = -3.4e38f, m1 = -3.4e38f;
    for (int i = e0 + lane; i < e1; i += 64){
      int s = srcP[i];
      float2 lv = *(const float2*)(el + (size_t)s*2);
      float v0 = lv.x + erv.x, v1 = lv.y + erv.y;
      v0 = (v0 > 0.f) ? v0 : 0.2f*v0;
      v1 = (v1 > 0.f) ? v1 : 0.2f*v1;
      m0 = fmaxf(m0, v0); m1 = fmaxf(m1, v1);
    }
    for (int k = 1; k < 64; k <<= 1){ m0 = fmaxf(m0, __shfl_xor(m0, k)); m1 = fmaxf(m1, __shfl_xor(m1, k)); }
    float s0 = 0.f, s1 = 0.f;
    for (int i = e0 + lane; i < e1; i += 64){
      int s = srcP[i];
      float2 lv = *(const float2*)(el + (size_t)s*2);
      float v0 = lv.x + erv.x, v1 = lv.y + erv.y;
      v0 = (v0 > 0.f) ? v0 : 0.2f*v0;
      v1 = (v1 > 0.f) ? v1 : 0.2f*v1;
      s0 += expf(v0 - m0); s1 += expf(v1 - m1);
    }
    for (int k = 1; k < 64; k <<= 1){ s0 += __shfl_xor(s0, k); s1 += __shfl_xor(s1, k); }
    float inv0 = (s0 > 0.f) ? 1.f/s0 : 0.f;
    float inv1 = (s1 > 0.f) ? 1.f/s1 : 0.f;
    for (int c0 = e0; c0 < e1; c0 += 64){
      int ce = e1 - c0; if (ce > 64) ce = 64;
      if (lane < ce){
        int s = srcP[c0 + lane];
        float2 lv = *(const float2*)(el + (size_t)s*2);
        float v0 = lv.x + erv.x, v1 = lv.y + erv.y;
        v0 = (v0 > 0.f) ? v0 : 0.2f*v0;
        v1 = (v1 > 0.f) ? v1 : 0.2f*v1;
        ss[wave][lane] = s;
        sw[wave][lane][0] = expf(v0 - m0) * inv0;
        sw[wave][lane][1] = expf(v1 - m1) * inv1;
      }
      for (int i = eighth; i < ce; i += 8){
        int s = ss[wave][i];
        float w = sw[wave][i][head];
        const uint4* hp = (const uint4*)(hpair8 + (size_t)s*256 + sub*32);
        uint4 h0 = hp[0], h1 = hp[1];
        float2v wv = { w, w };
        acc[0] += wv*__builtin_amdgcn_cvt_pk_f32_fp8(h0.x, false);
        acc[1] += wv*__builtin_amdgcn_cvt_pk_f32_fp8(h0.x, true);
        acc[2] += wv*__builtin_amdgcn_cvt_pk_f32_fp8(h0.y, false);
        acc[3] += wv*__builtin_amdgcn_cvt_pk_f32_fp8(h0.y, true);
        acc[4] += wv*__builtin_amdgcn_cvt_pk_f32_fp8(h0.z, false);
        acc[5] += wv*__builtin_amdgcn_cvt_pk_f32_fp8(h0.z, true);
        acc[6] += wv*__builtin_amdgcn_cvt_pk_f32_fp8(h0.w, false);
        acc[7] += wv*__builtin_amdgcn_cvt_pk_f32_fp8(h0.w, true);
        acc[8] += wv*__builtin_amdgcn_cvt_pk_f32_fp8(h1.x, false);
        acc[9] += wv*__builtin_amdgcn_cvt_pk_f32_fp8(h1.x, true);
        acc[10]+= wv*__builtin_amdgcn_cvt_pk_f32_fp8(h1.y, false);
        acc[11]+= wv*__builtin_amdgcn_cvt_pk_f32_fp8(h1.y, true);
        acc[12]+= wv*__builtin_amdgcn_cvt_pk_f32_fp8(h1.z, false);
        acc[13]+= wv*__builtin_amdgcn_cvt_pk_f32_fp8(h1.z, true);
        acc[14]+= wv*__builtin_amdgcn_cvt_pk_f32_fp8(h1.w, false);
        acc[15]+= wv*__builtin_amdgcn_cvt_pk_f32_fp8(h1.w, true);
      }
    }
  }

  // sum the 8 eighth-partials (all lanes end with the full sum)
  #pragma unroll
  for (int k = 0; k < 16; k++){
    #pragma unroll
    for (int d = 8; d < 64; d <<= 1){
      float2v t;
      t[0] = __shfl_xor(acc[k][0], d); t[1] = __shfl_xor(acc[k][1], d);
      acc[k] += t;
    }
  }
  float t[32];
  #pragma unroll
  for (int k = 0; k < 32; k++)
    t[k] = fmaxf(acc[k>>1][k&1] + bias[sub*32 + k], 0.f);
  float o[32];
  #pragma unroll
  for (int k = 0; k < 32; k++) o[k] = 0.5f*(t[k] + __shfl_xor(t[k], 4));
  if (lane < 4){
    ushort u[32];
    #pragma unroll
    for (int k = 0; k < 32; k++) u[k] = (ushort)f2bf_rne(o[k]);
    #pragma unroll
    for (int q = 0; q < 4; q++)
      *(uint4*)(outh + (size_t)n*128 + sub*32 + q*8) = *(uint4*)(u + q*8);
    float gp = 0.f;
    #pragma unroll
    for (int k = 0; k < 32; k++) gp += o[k]*gwv[sub*32 + k];
    gp += __shfl_xor(gp, 1);
    gp += __shfl_xor(gp, 2);
    if (sub == 0) gate[n] = gp + gbv[0];
  }
}

// ---------------- pool partial (fused stats) + reduce ----------------
#define POOL_P 32
__global__ __launch_bounds__(128) void k_pool_partial(const ushort* __restrict__ x,
    const float* __restrict__ gate, const int* __restrict__ gstart,
    float* __restrict__ partials){
  int b = blockIdx.x;
  int p = blockIdx.y;
  int n0 = gstart[b], n1 = gstart[b+1];
  int tid = threadIdx.x, lane = tid & 63, wid = tid >> 6;
  __shared__ float red[2];
  float m = -3.4e38f;
  for (int n = n0 + tid; n < n1; n += 128) m = fmaxf(m, gate[n]);
  for (int k = 1; k < 64; k <<= 1) m = fmaxf(m, __shfl_xor(m, k));
  if (lane == 0) red[wid] = m;
  __syncthreads();
  m = fmaxf(red[0], red[1]);
  __syncthreads();
  float s = 0.f;
  for (int n = n0 + tid; n < n1; n += 128) s += expf(gate[n] - m);
  for (int k = 1; k < 64; k <<= 1) s += __shfl_xor(s, k);
  if (lane == 0) red[wid] = s;
  __syncthreads();
  s = red[0] + red[1];
  float inv = (s > 0.f) ? 1.f/s : 0.f;
  float acc = 0.f;
  for (int n = n0 + p; n < n1; n += POOL_P){
    float w = expf(gate[n] - m) * inv;
    acc += w * bf2f(x[(size_t)n*128 + tid]);
  }
  partials[((size_t)b*POOL_P + p)*128 + tid] = acc;
}

__global__ __launch_bounds__(128) void k_pool_reduce(const float* __restrict__ partials,
    float* __restrict__ hg){
  int b = blockIdx.x;
  int tid = threadIdx.x;
  float s = 0.f;
  #pragma unroll
  for (int p = 0; p < POOL_P; p++) s += partials[((size_t)b*POOL_P + p)*128 + tid];
  hg[(size_t)b*128 + tid] = s;
}

// ---------------- fused LSTM (2 layers x 4 steps) + final head ----------------
__global__ __launch_bounds__(512) void k_lstm_all(const float* __restrict__ seq,
    const unsigned* __restrict__ Wxp, const unsigned* __restrict__ Whp,
    const float* __restrict__ bias2,
    const float* __restrict__ cw, const float* __restrict__ cb,
    float* __restrict__ out, int B){
  int b = blockIdx.x;
  int j = threadIdx.x;
  __shared__ float xs[4][128];
  __shared__ float gates[512];
  __shared__ float hcur[128], ccur[128];
  __shared__ float l0out[4][128];
  __shared__ float red[2];

  #pragma unroll
  for (int l = 0; l < 2; l++){
    const unsigned* Wx = Wxp + (size_t)l*32768;
    const unsigned* Wh = Whp + (size_t)l*32768;
    const float* bi = bias2 + l*512;
    { int t = j >> 7, k = j & 127;
      xs[t][k] = (l == 0) ? seq[(size_t)t*B*128 + (size_t)b*128 + k] : l0out[t][k];
      if (j < 128){ hcur[j] = 0.f; ccur[j] = 0.f; } }
    __syncthreads();
    float gx[4] = {0.f, 0.f, 0.f, 0.f};
    #pragma unroll 8
    for (int c = 0; c < 64; c++){
      unsigned w2 = Wx[c*512 + j];
      float wlo = __uint_as_float(w2 << 16);
      float whi = __uint_as_float(w2 & 0xffff0000u);
      #pragma unroll
      for (int t = 0; t < 4; t++)
        gx[t] += xs[t][2*c]*wlo + xs[t][2*c+1]*whi;
    }
    #pragma unroll
    for (int t = 0; t < 4; t++){
      float g = gx[t] + bi[j];
      #pragma unroll 8
      for (int c = 0; c < 64; c++){
        unsigned w2 = Wh[c*512 + j];
        g += hcur[2*c]*__uint_as_float(w2 << 16)
           + hcur[2*c+1]*__uint_as_float(w2 & 0xffff0000u);
      }
      gates[j] = g;
      __syncthreads();
      if (j < 128){
        float gi = sigmoidf_(gates[j]);
        float gf = sigmoidf_(gates[128 + j]);
        float gg = tanhf(gates[256 + j]);
        float go = sigmoidf_(gates[384 + j]);
        float c2 = gf * ccur[j] + gi * gg;
        float h = go * tanhf(c2);
        ccur[j] = c2;
        hcur[j] = h;
        if (l == 0) l0out[t][j] = h;
      }
      __syncthreads();
    }
  }
  float p = (j < 128) ? hcur[j] * cw[j] : 0.f;
  if (j < 128){
    for (int k = 1; k < 64; k <<= 1) p += __shfl_xor(p, k);
    if ((j & 63) == 0) red[j >> 6] = p;
  }
  __syncthreads();
  if (j == 0) out[b] = sigmoidf_(red[0] + red[1] + cb[0]);
}

extern "C" void kernel_launch(void* const* d_in, const int* in_sizes, int n_in,
                              void* d_out, int out_size, void* d_ws, size_t ws_size,
                              hipStream_t stream){
  const float* nfeats = (const float*)d_in[0];
  const int*   src    = (const int*)d_in[1];
  const int*   dst    = (const int*)d_in[2];
  const int*   ng     = (const int*)d_in[3];
  const float* Wm[3]  = { (const float*)d_in[4],  (const float*)d_in[8],  (const float*)d_in[12] };
  const float* al[3]  = { (const float*)d_in[5],  (const float*)d_in[9],  (const float*)d_in[13] };
  const float* ar[3]  = { (const float*)d_in[6],  (const float*)d_in[10], (const float*)d_in[14] };
  const float* bb[3]  = { (const float*)d_in[7],  (const float*)d_in[11], (const float*)d_in[15] };
  const float* gw[4]  = { (const float*)d_in[16], (const float*)d_in[18], (const float*)d_in[20], (const float*)d_in[22] };
  const float* gb[4]  = { (const float*)d_in[17], (const float*)d_in[19], (const float*)d_in[21], (const float*)d_in[23] };
  const float* Wih = (const float*)d_in[24];
  const float* Whh = (const float*)d_in[25];
  const float* bih = (const float*)d_in[26];
  const float* bhh = (const float*)d_in[27];
  const float* cw  = (const float*)d_in[28];
  const float* cb  = (const float*)d_in[29];

  const int N = in_sizes[3];      // 50000
  const int E = in_sizes[1];      // 800000
  const int B = out_size;         // 64

  char* p = (char*)d_ws;
  auto alloc = [&](size_t bytes) -> void* {
    void* q = (void*)p;
    p += (bytes + 255) & ~(size_t)255;
    return q;
  };
  unsigned char* hpair8 = (unsigned char*)alloc((size_t)N*256);
  ushort* aggh   = (ushort*)alloc((size_t)N*128*2);
  ushort* xh0    = (ushort*)alloc((size_t)N*128*2);
  ushort* Wt     = (ushort*)alloc((size_t)3*256*128*2);
  float*  el     = (float*)alloc((size_t)N*2*4);
  float*  er     = (float*)alloc((size_t)N*2*4);
  int*    srcP   = (int*)alloc((size_t)E*4);
  float*  gate   = (float*)alloc((size_t)N*4);
  int*    deg    = (int*)alloc((size_t)N*4);
  int*    offs   = (int*)alloc((size_t)(N+1)*4);
  int*    cnt    = (int*)alloc((size_t)N*4);
  int*    gstart = (int*)alloc((size_t)(B+1)*4);
  int*    csum   = (int*)alloc((size_t)64*4);
  int*    cpre   = (int*)alloc((size_t)64*4);
  float*  seqA   = (float*)alloc((size_t)4*B*128*4);
  float*  partials = (float*)alloc((size_t)B*POOL_P*128*4);
  unsigned* Wxp  = (unsigned*)alloc((size_t)2*64*512*4);
  unsigned* Whp  = (unsigned*)alloc((size_t)2*64*512*4);
  float*  bias2  = (float*)alloc((size_t)2*512*4);

  auto cdiv = [](int a, int b){ return (a + b - 1) / b; };
  const int NB = cdiv(N, CHUNK);   // 49 chunks

  hipMemsetAsync(deg, 0, (size_t)N*4, stream);
  hipMemsetAsync(cnt, 0, (size_t)N*4, stream);
  k_hist<<<cdiv(E,256), 256, 0, stream>>>(dst, deg, E);
  k_chunksum<<<NB, 256, 0, stream>>>(deg, csum, N);
  k_scan_small<<<1, 64, 0, stream>>>(csum, cpre, NB, offs + N);
  k_scan_apply<<<NB, 256, 0, stream>>>(deg, cpre, offs, N);
  k_scatter_src<<<cdiv(E,256), 256, 0, stream>>>(src, dst, offs, cnt, srcP, E);
  k_graph_bounds<<<cdiv(N,256), 256, 0, stream>>>(ng, gstart, N, B);

  // conversions + fused layer-0 gate
  k_tobf16_gate<<<cdiv(N,4), 256, 0, stream>>>(nfeats, gw[0], gb[0], xh0, gate, N);
  for (int l = 0; l < 3; l++)
    k_wt<<<cdiv(256*128, 256), 256, 0, stream>>>(Wm[l], Wt + (size_t)l*256*128, 256*128);
  k_lstm_prep<<<cdiv(131072, 256), 256, 0, stream>>>(Wih, Whh, bih, bhh, Wxp, Whp, bias2);

  auto pool_rest = [&](const ushort* xv, float* hgv){
    dim3 pg(B, POOL_P);
    k_pool_partial<<<pg, 128, 0, stream>>>(xv, gate, gstart, partials);
    k_pool_reduce<<<B, 128, 0, stream>>>(partials, hgv);
  };

  // pool 0 on raw features (bf16 copy)
  pool_rest(xh0, seqA + 0*(size_t)B*128);

  const ushort* xh = xh0;
  const int strips = cdiv(N, 16);
  for (int layer = 0; layer < 3; layer++){
    k_gemm_mfma<<<cdiv(strips,4), 256, 0, stream>>>(xh, Wt + (size_t)layer*256*128,
        al[layer], ar[layer], hpair8, el, er, N);
    k_aggregate<<<cdiv(N,4), 256, 0, stream>>>(hpair8, el, er, srcP, offs,
        bb[layer], gw[layer+1], gb[layer+1], aggh, gate, N);
    pool_rest(aggh, seqA + (size_t)(layer+1)*B*128);
    xh = aggh;
  }

  k_lstm_all<<<B, 512, 0, stream>>>(seqA, Wxp, Whp, bias2, cw, cb, (float*)d_out, B);
}

// Round 14
// 431.642 us; speedup vs baseline: 1.3186x; 1.3186x over previous
//
#include <hip/hip_runtime.h>
#include <cmath>

// N=50000 nodes, E=800000 edges, B=64 graphs, H=2 heads, D=128, FIN=128, L=2.

typedef __attribute__((ext_vector_type(8))) short short8v;   // 8 x bf16 (4 VGPRs)
typedef __attribute__((ext_vector_type(4))) float float4v;   // MFMA acc
typedef __attribute__((ext_vector_type(2))) float float2v;   // packed f32 pair

__device__ __forceinline__ float sigmoidf_(float x){ return 1.f/(1.f+expf(-x)); }

__device__ __forceinline__ unsigned f2bf_rne(float f){
  unsigned u = __float_as_uint(f);
  return (u + 0x7fffu + ((u >> 16) & 1u)) >> 16;   // round-nearest-even bf16
}
__device__ __forceinline__ float bf2f(ushort v){ return __uint_as_float((unsigned)v << 16); }
// fp8 e4m3 (hardware cvt, OCP on gfx950; encode+decode use the same HW format)
__device__ __forceinline__ unsigned char f2fp8(float f){
  unsigned v = __builtin_amdgcn_cvt_pk_fp8_f32(f, f, 0, false);
  return (unsigned char)(v & 0xffu);
}

// ---------------- CSR build (by dst) ----------------
__global__ void k_hist(const int* __restrict__ dst, int* __restrict__ deg, int E){
  int e = blockIdx.x*blockDim.x + threadIdx.x;
  if (e < E) atomicAdd(&deg[dst[e]], 1);
}

// parallel exclusive scan: chunk sums -> tiny scan -> apply
#define CHUNK 1024
__global__ __launch_bounds__(256) void k_chunksum(const int* __restrict__ in, int* __restrict__ csum, int n){
  int b = blockIdx.x;
  int tid = threadIdx.x;
  int v = 0;
  #pragma unroll
  for (int k = 0; k < 4; k++){
    int i = b*CHUNK + tid + k*256;
    if (i < n) v += in[i];
  }
  for (int d = 1; d < 64; d <<= 1) v += __shfl_xor(v, d);
  __shared__ int ws[4];
  if ((tid & 63) == 0) ws[tid>>6] = v;
  __syncthreads();
  if (tid == 0) csum[b] = ws[0]+ws[1]+ws[2]+ws[3];
}

__global__ void k_scan_small(const int* __restrict__ csum, int* __restrict__ cpre, int nb,
                             int* __restrict__ total_out){
  int lane = threadIdx.x;  // 64 threads, nb <= 64
  int v = (lane < nb) ? csum[lane] : 0;
  int incl = v;
  for (int d = 1; d < 64; d <<= 1){ int t = __shfl_up(incl, d); if (lane >= d) incl += t; }
  if (lane < nb) cpre[lane] = incl - v;
  if (lane == 63) *total_out = incl;
}

__global__ __launch_bounds__(256) void k_scan_apply(const int* __restrict__ in, const int* __restrict__ cpre,
                                                    int* __restrict__ offs, int n){
  int b = blockIdx.x;
  int tid = threadIdx.x, lane = tid & 63, wid = tid >> 6;
  int x[4];
  int s = 0;
  #pragma unroll
  for (int k = 0; k < 4; k++){
    int i = b*CHUNK + tid*4 + k;
    x[k] = (i < n) ? in[i] : 0;
    s += x[k];
  }
  int incl = s;
  for (int d = 1; d < 64; d <<= 1){ int t = __shfl_up(incl, d); if (lane >= d) incl += t; }
  __shared__ int ws[4];
  if (lane == 63) ws[wid] = incl;
  __syncthreads();
  int wpre = 0;
  for (int w = 0; w < wid; w++) wpre += ws[w];
  int base = cpre[b] + wpre + incl - s;
  #pragma unroll
  for (int k = 0; k < 4; k++){
    int i = b*CHUNK + tid*4 + k;
    if (i < n) offs[i] = base;
    base += x[k];
  }
}

// scatter src ids into CSR slot order (layer-invariant, built once)
__global__ void k_scatter_src(const int* __restrict__ src, const int* __restrict__ dst,
                              const int* __restrict__ offs, int* __restrict__ cnt,
                              int* __restrict__ srcP, int E){
  int e = blockIdx.x*blockDim.x + threadIdx.x;
  if (e < E){ int d = dst[e]; int p = atomicAdd(&cnt[d], 1); srcP[offs[d] + p] = src[e]; }
}

__global__ void k_graph_bounds(const int* __restrict__ ng, int* __restrict__ gstart, int n, int nb){
  int i = blockIdx.x*blockDim.x + threadIdx.x;
  if (i >= n) return;
  int g = ng[i];
  int gp = (i == 0) ? -1 : ng[i-1];
  for (int b = gp+1; b <= g; b++) gstart[b] = i;
  if (i == n-1) for (int b = g+1; b <= nb; b++) gstart[b] = n;
}

// ---------------- fused nfeats->bf16 + layer-0 pool gate (wave per node) ----------------
__global__ __launch_bounds__(256) void k_tobf16_gate(const float* __restrict__ in,
    const float* __restrict__ gw, const float* __restrict__ gb,
    ushort* __restrict__ out, float* __restrict__ gate, int Nn){
  int n = blockIdx.x*4 + (threadIdx.x >> 6);
  if (n >= Nn) return;
  int lane = threadIdx.x & 63;
  float2 v = *(const float2*)(in + (size_t)n*128 + lane*2);
  unsigned pk = (f2bf_rne(v.y) << 16) | f2bf_rne(v.x);
  *(unsigned*)(out + (size_t)n*128 + lane*2) = pk;
  float2 gv = *(const float2*)(gw + lane*2);
  float p = v.x*gv.x + v.y*gv.y;
  for (int k = 1; k < 64; k <<= 1) p += __shfl_xor(p, k);
  if (lane == 0) gate[n] = p + gb[0];
}

// W [128,256] f32 -> Wt [256,128] bf16
__global__ void k_wt(const float* __restrict__ W, ushort* __restrict__ Wt, int total){
  int idx = blockIdx.x*blockDim.x + threadIdx.x;
  if (idx >= total) return;
  int c = idx >> 7;
  int k = idx & 127;
  Wt[idx] = (ushort)f2bf_rne(W[(size_t)k*256 + c]);
}

// LSTM weight prep: packed bf16 pairs.
__global__ void k_lstm_prep(const float* __restrict__ Wih, const float* __restrict__ Whh,
                            const float* __restrict__ bih, const float* __restrict__ bhh,
                            unsigned* __restrict__ Wxp, unsigned* __restrict__ Whp,
                            float* __restrict__ bias2){
  int idx = blockIdx.x*blockDim.x + threadIdx.x;   // 2*2*64*512 = 131072
  if (idx >= 131072) return;
  int j   = idx & 511;
  int c   = (idx >> 9) & 63;
  int isH = (idx >> 15) & 1;
  int l   = idx >> 16;
  const float* srcW = isH ? Whh : Wih;
  float w0 = srcW[(size_t)l*512*128 + (size_t)j*128 + 2*c];
  float w1 = srcW[(size_t)l*512*128 + (size_t)j*128 + 2*c + 1];
  unsigned v = (f2bf_rne(w1) << 16) | f2bf_rne(w0);
  unsigned* dst = isH ? Whp : Wxp;
  dst[(size_t)l*32768 + c*512 + j] = v;
  if (!isH && c == 0) bias2[l*512 + j] = bih[l*512 + j] + bhh[l*512 + j];
}

// ---------------- MFMA GEMM (Wt staged in LDS): Y8[M,256](fp8) = Xh[M,128] @ W, fused el/er ----------------
// LDS layout [c=0..15][row=0..255][8 ushorts]: quarter-wave reads 16 contiguous rows -> conflict-free.
__global__ __launch_bounds__(256) void k_gemm_mfma(const ushort* __restrict__ Xh,
    const ushort* __restrict__ Wt, const float* __restrict__ alv, const float* __restrict__ arv,
    unsigned char* __restrict__ Y8, float* __restrict__ el, float* __restrict__ er, int M){
  __shared__ ushort WlS[16*256*8];   // 64 KB
  int tid = threadIdx.x;
  #pragma unroll
  for (int i = 0; i < 16; i++){
    int g = i*256 + tid;
    int row = g >> 4, c = g & 15;
    *(uint4*)(WlS + ((size_t)c*256 + row)*8) = *(const uint4*)(Wt + (size_t)row*128 + c*8);
  }
  __syncthreads();
  int wave = tid >> 6;
  int lane = tid & 63;
  int strip = blockIdx.x*4 + wave;
  if (strip*16 >= M) return;
  int m0 = strip*16;
  int l15 = lane & 15;
  int kg  = lane >> 4;
  int arow = m0 + l15; if (arow >= M) arow = M-1;
  short8v a[4];
  const ushort* xrow = Xh + (size_t)arow*128 + kg*8;
  #pragma unroll
  for (int ks = 0; ks < 4; ks++) a[ks] = *(const short8v*)(xrow + ks*32);
  float4v acc[16];
  #pragma unroll
  for (int nt = 0; nt < 16; nt++) acc[nt] = (float4v){0.f,0.f,0.f,0.f};
  #pragma unroll
  for (int nt = 0; nt < 16; nt++){
    #pragma unroll
    for (int ks = 0; ks < 4; ks++){
      short8v b = *(const short8v*)(WlS + (((size_t)(kg + ks*4)*256) + nt*16 + l15)*8);
      acc[nt] = __builtin_amdgcn_mfma_f32_16x16x32_bf16(a[ks], b, acc[nt], 0, 0, 0);
    }
  }
  float pel0[4]={0,0,0,0}, pel1[4]={0,0,0,0}, per0[4]={0,0,0,0}, per1[4]={0,0,0,0};
  #pragma unroll
  for (int nt = 0; nt < 16; nt++){
    int col = nt*16 + l15;
    float av = alv[col], rv = arv[col];
    #pragma unroll
    for (int j = 0; j < 4; j++){
      float v = acc[nt][j];
      int r = m0 + kg*4 + j;
      if (r < M) Y8[(size_t)r*256 + col] = f2fp8(v);
      if (nt < 8){ pel0[j] += v*av; per0[j] += v*rv; }
      else       { pel1[j] += v*av; per1[j] += v*rv; }
    }
  }
  #pragma unroll
  for (int j = 0; j < 4; j++){
    #pragma unroll
    for (int d = 1; d < 16; d <<= 1){
      pel0[j] += __shfl_xor(pel0[j], d);
      pel1[j] += __shfl_xor(pel1[j], d);
      per0[j] += __shfl_xor(per0[j], d);
      per1[j] += __shfl_xor(per1[j], d);
    }
  }
  if (l15 == 0){
    #pragma unroll
    for (int j = 0; j < 4; j++){
      int r = m0 + kg*4 + j;
      if (r < M){
        el[(size_t)r*2+0] = pel0[j];
        el[(size_t)r*2+1] = pel1[j];
        er[(size_t)r*2+0] = per0[j];
        er[(size_t)r*2+1] = per1[j];
      }
    }
  }
}

// ---------------- softmax + aggregate (in-kernel scores, fp8 gather, 4 edges/iter, 16B/lane) ----------------
// quarter = lane>>4 picks edge i+quarter; sub = lane&15 covers 16 dims of flat 256 (head = sub>>3).
#define MAXE 256
__global__ __launch_bounds__(256) void k_aggregate(const unsigned char* __restrict__ hpair8,
    const float* __restrict__ el, const float* __restrict__ er,
    const int* __restrict__ srcP, const int* __restrict__ offs,
    const float* __restrict__ bias, const float* __restrict__ gwv, const float* __restrict__ gbv,
    ushort* __restrict__ outh, float* __restrict__ gate, int Nn){
  __shared__ float sw[4][MAXE][2];   // scores -> weights (8 KB)
  __shared__ int   ss[4][MAXE];      // src ids (4 KB)
  int wave = threadIdx.x >> 6;
  int n = blockIdx.x*4 + wave;
  if (n >= Nn) return;
  int lane = threadIdx.x & 63;
  int e0 = offs[n], e1 = offs[n+1];
  int deg = e1 - e0;
  int quarter = lane >> 4;     // which edge of the 4-pack
  int sub     = lane & 15;     // 16-dim slice of flat 256
  int head    = sub >> 3;
  float2 erv = *(const float2*)(er + (size_t)n*2);
  float2v acc[8];
  #pragma unroll
  for (int k = 0; k < 8; k++) acc[k] = (float2v){0.f, 0.f};

  if (deg <= MAXE){
    float m0 = -3.4e38f, m1 = -3.4e38f;
    for (int i = lane; i < deg; i += 64){
      int s = srcP[e0 + i];
      ss[wave][i] = s;
      float2 lv = *(const float2*)(el + (size_t)s*2);
      float v0 = lv.x + erv.x, v1 = lv.y + erv.y;
      v0 = (v0 > 0.f) ? v0 : 0.2f*v0;
      v1 = (v1 > 0.f) ? v1 : 0.2f*v1;
      sw[wave][i][0] = v0; sw[wave][i][1] = v1;
      m0 = fmaxf(m0, v0); m1 = fmaxf(m1, v1);
    }
    for (int k = 1; k < 64; k <<= 1){ m0 = fmaxf(m0, __shfl_xor(m0, k)); m1 = fmaxf(m1, __shfl_xor(m1, k)); }
    float s0 = 0.f, s1 = 0.f;
    for (int i = lane; i < deg; i += 64){
      s0 += expf(sw[wave][i][0] - m0);
      s1 += expf(sw[wave][i][1] - m1);
    }
    for (int k = 1; k < 64; k <<= 1){ s0 += __shfl_xor(s0, k); s1 += __shfl_xor(s1, k); }
    float inv0 = (s0 > 0.f) ? 1.f/s0 : 0.f;
    float inv1 = (s1 > 0.f) ? 1.f/s1 : 0.f;
    for (int i = lane; i < deg; i += 64){
      sw[wave][i][0] = expf(sw[wave][i][0] - m0) * inv0;
      sw[wave][i][1] = expf(sw[wave][i][1] - m1) * inv1;
    }
    // gather (wave-internal LDS producer->consumer: no barrier needed)
    for (int i = quarter; i < deg; i += 4){
      int s = ss[wave][i];
      float w = sw[wave][i][head];
      uint4 hv = *(const uint4*)(hpair8 + (size_t)s*256 + sub*16);
      float2v wv = { w, w };
      acc[0] += wv*__builtin_amdgcn_cvt_pk_f32_fp8(hv.x, false);
      acc[1] += wv*__builtin_amdgcn_cvt_pk_f32_fp8(hv.x, true);
      acc[2] += wv*__builtin_amdgcn_cvt_pk_f32_fp8(hv.y, false);
      acc[3] += wv*__builtin_amdgcn_cvt_pk_f32_fp8(hv.y, true);
      acc[4] += wv*__builtin_amdgcn_cvt_pk_f32_fp8(hv.z, false);
      acc[5] += wv*__builtin_amdgcn_cvt_pk_f32_fp8(hv.z, true);
      acc[6] += wv*__builtin_amdgcn_cvt_pk_f32_fp8(hv.w, false);
      acc[7] += wv*__builtin_amdgcn_cvt_pk_f32_fp8(hv.w, true);
    }
  } else {
    // slow path (deg > MAXE): recompute per chunk
    float m0 = -3.4e38f, m1 = -3.4e38f;
    for (int i = e0 + lane; i < e1; i += 64){
      int s = srcP[i];
      float2 lv = *(const float2*)(el + (size_t)s*2);
      float v0 = lv.x + erv.x, v1 = lv.y + erv.y;
      v0 = (v0 > 0.f) ? v0 : 0.2f*v0;
      v1 = (v1 > 0.f) ? v1 : 0.2f*v1;
      m0 = fmaxf(m0, v0); m1 = fmaxf(m1, v1);
    }
    for (int k = 1; k < 64; k <<= 1){ m0 = fmaxf(m0, __shfl_xor(m0, k)); m1 = fmaxf(m1, __shfl_xor(m1, k)); }
    float s0 = 0.f, s1 = 0.f;
    for (int i = e0 + lane; i < e1; i += 64){
      int s = srcP[i];
      float2 lv = *(const float2*)(el + (size_t)s*2);
      float v0 = lv.x + erv.x, v1 = lv.y + erv.y;
      v0 = (v0 > 0.f) ? v0 : 0.2f*v0;
      v1 = (v1 > 0.f) ? v1 : 0.2f*v1;
      s0 += expf(v0 - m0); s1 += expf(v1 - m1);
    }
    for (int k = 1; k < 64; k <<= 1){ s0 += __shfl_xor(s0, k); s1 += __shfl_xor(s1, k); }
    float inv0 = (s0 > 0.f) ? 1.f/s0 : 0.f;
    float inv1 = (s1 > 0.f) ? 1.f/s1 : 0.f;
    for (int c0 = e0; c0 < e1; c0 += 64){
      int ce = e1 - c0; if (ce > 64) ce = 64;
      if (lane < ce){
        int s = srcP[c0 + lane];
        float2 lv = *(const float2*)(el + (size_t)s*2);
        float v0 = lv.x + erv.x, v1 = lv.y + erv.y;
        v0 = (v0 > 0.f) ? v0 : 0.2f*v0;
        v1 = (v1 > 0.f) ? v1 : 0.2f*v1;
        ss[wave][lane] = s;
        sw[wave][lane][0] = expf(v0 - m0) * inv0;
        sw[wave][lane][1] = expf(v1 - m1) * inv1;
      }
      for (int i = quarter; i < ce; i += 4){
        int s = ss[wave][i];
        float w = sw[wave][i][head];
        uint4 hv = *(const uint4*)(hpair8 + (size_t)s*256 + sub*16);
        float2v wv = { w, w };
        acc[0] += wv*__builtin_amdgcn_cvt_pk_f32_fp8(hv.x, false);
        acc[1] += wv*__builtin_amdgcn_cvt_pk_f32_fp8(hv.x, true);
        acc[2] += wv*__builtin_amdgcn_cvt_pk_f32_fp8(hv.y, false);
        acc[3] += wv*__builtin_amdgcn_cvt_pk_f32_fp8(hv.y, true);
        acc[4] += wv*__builtin_amdgcn_cvt_pk_f32_fp8(hv.z, false);
        acc[5] += wv*__builtin_amdgcn_cvt_pk_f32_fp8(hv.z, true);
        acc[6] += wv*__builtin_amdgcn_cvt_pk_f32_fp8(hv.w, false);
        acc[7] += wv*__builtin_amdgcn_cvt_pk_f32_fp8(hv.w, true);
      }
    }
  }

  // sum the 4 quarter-partials (all lanes end with the full sum)
  #pragma unroll
  for (int k = 0; k < 8; k++){
    float2v t16, t32;
    t16[0] = __shfl_xor(acc[k][0], 16); t16[1] = __shfl_xor(acc[k][1], 16);
    acc[k] += t16;
    t32[0] = __shfl_xor(acc[k][0], 32); t32[1] = __shfl_xor(acc[k][1], 32);
    acc[k] += t32;
  }
  float t[16];
  #pragma unroll
  for (int k = 0; k < 16; k++)
    t[k] = fmaxf(acc[k>>1][k&1] + bias[sub*16 + k], 0.f);
  float o[16];
  #pragma unroll
  for (int k = 0; k < 16; k++) o[k] = 0.5f*(t[k] + __shfl_xor(t[k], 8));
  if (lane < 8){
    ushort u[16];
    #pragma unroll
    for (int k = 0; k < 16; k++) u[k] = (ushort)f2bf_rne(o[k]);
    *(uint4*)(outh + (size_t)n*128 + sub*16)     = *(uint4*)u;
    *(uint4*)(outh + (size_t)n*128 + sub*16 + 8) = *(uint4*)(u + 8);
    float gp = 0.f;
    #pragma unroll
    for (int k = 0; k < 16; k++) gp += o[k]*gwv[sub*16 + k];
    #pragma unroll
    for (int d = 1; d < 8; d <<= 1) gp += __shfl_xor(gp, d);
    if (sub == 0) gate[n] = gp + gbv[0];
  }
}

// ---------------- pool partial (fused stats) + reduce ----------------
#define POOL_P 32
__global__ __launch_bounds__(128) void k_pool_partial(const ushort* __restrict__ x,
    const float* __restrict__ gate, const int* __restrict__ gstart,
    float* __restrict__ partials){
  int b = blockIdx.x;
  int p = blockIdx.y;
  int n0 = gstart[b], n1 = gstart[b+1];
  int tid = threadIdx.x, lane = tid & 63, wid = tid >> 6;
  __shared__ float red[2];
  float m = -3.4e38f;
  for (int n = n0 + tid; n < n1; n += 128) m = fmaxf(m, gate[n]);
  for (int k = 1; k < 64; k <<= 1) m = fmaxf(m, __shfl_xor(m, k));
  if (lane == 0) red[wid] = m;
  __syncthreads();
  m = fmaxf(red[0], red[1]);
  __syncthreads();
  float s = 0.f;
  for (int n = n0 + tid; n < n1; n += 128) s += expf(gate[n] - m);
  for (int k = 1; k < 64; k <<= 1) s += __shfl_xor(s, k);
  if (lane == 0) red[wid] = s;
  __syncthreads();
  s = red[0] + red[1];
  float inv = (s > 0.f) ? 1.f/s : 0.f;
  float acc = 0.f;
  for (int n = n0 + p; n < n1; n += POOL_P){
    float w = expf(gate[n] - m) * inv;
    acc += w * bf2f(x[(size_t)n*128 + tid]);
  }
  partials[((size_t)b*POOL_P + p)*128 + tid] = acc;
}

__global__ __launch_bounds__(128) void k_pool_reduce(const float* __restrict__ partials,
    float* __restrict__ hg){
  int b = blockIdx.x;
  int tid = threadIdx.x;
  float s = 0.f;
  #pragma unroll
  for (int p = 0; p < POOL_P; p++) s += partials[((size_t)b*POOL_P + p)*128 + tid];
  hg[(size_t)b*128 + tid] = s;
}

// ---------------- fused LSTM (2 layers x 4 steps) + final head ----------------
__global__ __launch_bounds__(512) void k_lstm_all(const float* __restrict__ seq,
    const unsigned* __restrict__ Wxp, const unsigned* __restrict__ Whp,
    const float* __restrict__ bias2,
    const float* __restrict__ cw, const float* __restrict__ cb,
    float* __restrict__ out, int B){
  int b = blockIdx.x;
  int j = threadIdx.x;
  __shared__ float xs[4][128];
  __shared__ float gates[512];
  __shared__ float hcur[128], ccur[128];
  __shared__ float l0out[4][128];
  __shared__ float red[2];

  #pragma unroll
  for (int l = 0; l < 2; l++){
    const unsigned* Wx = Wxp + (size_t)l*32768;
    const unsigned* Wh = Whp + (size_t)l*32768;
    const float* bi = bias2 + l*512;
    { int t = j >> 7, k = j & 127;
      xs[t][k] = (l == 0) ? seq[(size_t)t*B*128 + (size_t)b*128 + k] : l0out[t][k];
      if (j < 128){ hcur[j] = 0.f; ccur[j] = 0.f; } }
    __syncthreads();
    float gx[4] = {0.f, 0.f, 0.f, 0.f};
    #pragma unroll 8
    for (int c = 0; c < 64; c++){
      unsigned w2 = Wx[c*512 + j];
      float wlo = __uint_as_float(w2 << 16);
      float whi = __uint_as_float(w2 & 0xffff0000u);
      #pragma unroll
      for (int t = 0; t < 4; t++)
        gx[t] += xs[t][2*c]*wlo + xs[t][2*c+1]*whi;
    }
    #pragma unroll
    for (int t = 0; t < 4; t++){
      float g = gx[t] + bi[j];
      #pragma unroll 8
      for (int c = 0; c < 64; c++){
        unsigned w2 = Wh[c*512 + j];
        g += hcur[2*c]*__uint_as_float(w2 << 16)
           + hcur[2*c+1]*__uint_as_float(w2 & 0xffff0000u);
      }
      gates[j] = g;
      __syncthreads();
      if (j < 128){
        float gi = sigmoidf_(gates[j]);
        float gf = sigmoidf_(gates[128 + j]);
        float gg = tanhf(gates[256 + j]);
        float go = sigmoidf_(gates[384 + j]);
        float c2 = gf * ccur[j] + gi * gg;
        float h = go * tanhf(c2);
        ccur[j] = c2;
        hcur[j] = h;
        if (l == 0) l0out[t][j] = h;
      }
      __syncthreads();
    }
  }
  float p = (j < 128) ? hcur[j] * cw[j] : 0.f;
  if (j < 128){
    for (int k = 1; k < 64; k <<= 1) p += __shfl_xor(p, k);
    if ((j & 63) == 0) red[j >> 6] = p;
  }
  __syncthreads();
  if (j == 0) out[b] = sigmoidf_(red[0] + red[1] + cb[0]);
}

extern "C" void kernel_launch(void* const* d_in, const int* in_sizes, int n_in,
                              void* d_out, int out_size, void* d_ws, size_t ws_size,
                              hipStream_t stream){
  const float* nfeats = (const float*)d_in[0];
  const int*   src    = (const int*)d_in[1];
  const int*   dst    = (const int*)d_in[2];
  const int*   ng     = (const int*)d_in[3];
  const float* Wm[3]  = { (const float*)d_in[4],  (const float*)d_in[8],  (const float*)d_in[12] };
  const float* al[3]  = { (const float*)d_in[5],  (const float*)d_in[9],  (const float*)d_in[13] };
  const float* ar[3]  = { (const float*)d_in[6],  (const float*)d_in[10], (const float*)d_in[14] };
  const float* bb[3]  = { (const float*)d_in[7],  (const float*)d_in[11], (const float*)d_in[15] };
  const float* gw[4]  = { (const float*)d_in[16], (const float*)d_in[18], (const float*)d_in[20], (const float*)d_in[22] };
  const float* gb[4]  = { (const float*)d_in[17], (const float*)d_in[19], (const float*)d_in[21], (const float*)d_in[23] };
  const float* Wih = (const float*)d_in[24];
  const float* Whh = (const float*)d_in[25];
  const float* bih = (const float*)d_in[26];
  const float* bhh = (const float*)d_in[27];
  const float* cw  = (const float*)d_in[28];
  const float* cb  = (const float*)d_in[29];

  const int N = in_sizes[3];      // 50000
  const int E = in_sizes[1];      // 800000
  const int B = out_size;         // 64

  char* p = (char*)d_ws;
  auto alloc = [&](size_t bytes) -> void* {
    void* q = (void*)p;
    p += (bytes + 255) & ~(size_t)255;
    return q;
  };
  unsigned char* hpair8 = (unsigned char*)alloc((size_t)N*256);
  ushort* aggh   = (ushort*)alloc((size_t)N*128*2);
  ushort* xh0    = (ushort*)alloc((size_t)N*128*2);
  ushort* Wt     = (ushort*)alloc((size_t)3*256*128*2);
  float*  el     = (float*)alloc((size_t)N*2*4);
  float*  er     = (float*)alloc((size_t)N*2*4);
  int*    srcP   = (int*)alloc((size_t)E*4);
  float*  gate   = (float*)alloc((size_t)N*4);
  int*    deg    = (int*)alloc((size_t)N*4);
  int*    offs   = (int*)alloc((size_t)(N+1)*4);
  int*    cnt    = (int*)alloc((size_t)N*4);
  int*    gstart = (int*)alloc((size_t)(B+1)*4);
  int*    csum   = (int*)alloc((size_t)64*4);
  int*    cpre   = (int*)alloc((size_t)64*4);
  float*  seqA   = (float*)alloc((size_t)4*B*128*4);
  float*  partials = (float*)alloc((size_t)B*POOL_P*128*4);
  unsigned* Wxp  = (unsigned*)alloc((size_t)2*64*512*4);
  unsigned* Whp  = (unsigned*)alloc((size_t)2*64*512*4);
  float*  bias2  = (float*)alloc((size_t)2*512*4);

  auto cdiv = [](int a, int b){ return (a + b - 1) / b; };
  const int NB = cdiv(N, CHUNK);   // 49 chunks

  hipMemsetAsync(deg, 0, (size_t)N*4, stream);
  hipMemsetAsync(cnt, 0, (size_t)N*4, stream);
  k_hist<<<cdiv(E,256), 256, 0, stream>>>(dst, deg, E);
  k_chunksum<<<NB, 256, 0, stream>>>(deg, csum, N);
  k_scan_small<<<1, 64, 0, stream>>>(csum, cpre, NB, offs + N);
  k_scan_apply<<<NB, 256, 0, stream>>>(deg, cpre, offs, N);
  k_scatter_src<<<cdiv(E,256), 256, 0, stream>>>(src, dst, offs, cnt, srcP, E);
  k_graph_bounds<<<cdiv(N,256), 256, 0, stream>>>(ng, gstart, N, B);

  // conversions + fused layer-0 gate
  k_tobf16_gate<<<cdiv(N,4), 256, 0, stream>>>(nfeats, gw[0], gb[0], xh0, gate, N);
  for (int l = 0; l < 3; l++)
    k_wt<<<cdiv(256*128, 256), 256, 0, stream>>>(Wm[l], Wt + (size_t)l*256*128, 256*128);
  k_lstm_prep<<<cdiv(131072, 256), 256, 0, stream>>>(Wih, Whh, bih, bhh, Wxp, Whp, bias2);

  auto pool_rest = [&](const ushort* xv, float* hgv){
    dim3 pg(B, POOL_P);
    k_pool_partial<<<pg, 128, 0, stream>>>(xv, gate, gstart, partials);
    k_pool_reduce<<<B, 128, 0, stream>>>(partials, hgv);
  };

  // pool 0 on raw features (bf16 copy)
  pool_rest(xh0, seqA + 0*(size_t)B*128);

  const ushort* xh = xh0;
  const int strips = cdiv(N, 16);
  for (int layer = 0; layer < 3; layer++){
    k_gemm_mfma<<<cdiv(strips,4), 256, 0, stream>>>(xh, Wt + (size_t)layer*256*128,
        al[layer], ar[layer], hpair8, el, er, N);
    k_aggregate<<<cdiv(N,4), 256, 0, stream>>>(hpair8, el, er, srcP, offs,
        bb[layer], gw[layer+1], gb[layer+1], aggh, gate, N);
    pool_rest(aggh, seqA + (size_t)(layer+1)*B*128);
    xh = aggh;
  }

  k_lstm_all<<<B, 512, 0, stream>>>(seqA, Wxp, Whp, bias2, cw, cb, (float*)d_out, B);
}

// Round 15
// 422.797 us; speedup vs baseline: 1.3462x; 1.0209x over previous
//
#include <hip/hip_runtime.h>
#include <cmath>

// N=50000 nodes, E=800000 edges, B=64 graphs, H=2 heads, D=128, FIN=128, L=2.

typedef __attribute__((ext_vector_type(8))) short short8v;   // 8 x bf16 (4 VGPRs)
typedef __attribute__((ext_vector_type(4))) float float4v;   // MFMA acc
typedef __attribute__((ext_vector_type(2))) float float2v;   // packed f32 pair

__device__ __forceinline__ float sigmoidf_(float x){ return 1.f/(1.f+expf(-x)); }
__device__ __forceinline__ float fexp(float x){ return __expf(x); }   // v_exp_f32 path

__device__ __forceinline__ unsigned f2bf_rne(float f){
  unsigned u = __float_as_uint(f);
  return (u + 0x7fffu + ((u >> 16) & 1u)) >> 16;   // round-nearest-even bf16
}
__device__ __forceinline__ float bf2f(ushort v){ return __uint_as_float((unsigned)v << 16); }
// fp8 e4m3 (hardware cvt, OCP on gfx950; encode+decode use the same HW format)
__device__ __forceinline__ unsigned char f2fp8(float f){
  unsigned v = __builtin_amdgcn_cvt_pk_fp8_f32(f, f, 0, false);
  return (unsigned char)(v & 0xffu);
}

// ---------------- CSR build (by dst) ----------------
__global__ void k_hist(const int* __restrict__ dst, int* __restrict__ deg, int E){
  int e = blockIdx.x*blockDim.x + threadIdx.x;
  if (e < E) atomicAdd(&deg[dst[e]], 1);
}

// parallel exclusive scan: chunk sums -> tiny scan -> apply
#define CHUNK 1024
__global__ __launch_bounds__(256) void k_chunksum(const int* __restrict__ in, int* __restrict__ csum, int n){
  int b = blockIdx.x;
  int tid = threadIdx.x;
  int v = 0;
  #pragma unroll
  for (int k = 0; k < 4; k++){
    int i = b*CHUNK + tid + k*256;
    if (i < n) v += in[i];
  }
  for (int d = 1; d < 64; d <<= 1) v += __shfl_xor(v, d);
  __shared__ int ws[4];
  if ((tid & 63) == 0) ws[tid>>6] = v;
  __syncthreads();
  if (tid == 0) csum[b] = ws[0]+ws[1]+ws[2]+ws[3];
}

__global__ void k_scan_small(const int* __restrict__ csum, int* __restrict__ cpre, int nb,
                             int* __restrict__ total_out){
  int lane = threadIdx.x;  // 64 threads, nb <= 64
  int v = (lane < nb) ? csum[lane] : 0;
  int incl = v;
  for (int d = 1; d < 64; d <<= 1){ int t = __shfl_up(incl, d); if (lane >= d) incl += t; }
  if (lane < nb) cpre[lane] = incl - v;
  if (lane == 63) *total_out = incl;
}

__global__ __launch_bounds__(256) void k_scan_apply(const int* __restrict__ in, const int* __restrict__ cpre,
                                                    int* __restrict__ offs, int n){
  int b = blockIdx.x;
  int tid = threadIdx.x, lane = tid & 63, wid = tid >> 6;
  int x[4];
  int s = 0;
  #pragma unroll
  for (int k = 0; k < 4; k++){
    int i = b*CHUNK + tid*4 + k;
    x[k] = (i < n) ? in[i] : 0;
    s += x[k];
  }
  int incl = s;
  for (int d = 1; d < 64; d <<= 1){ int t = __shfl_up(incl, d); if (lane >= d) incl += t; }
  __shared__ int ws[4];
  if (lane == 63) ws[wid] = incl;
  __syncthreads();
  int wpre = 0;
  for (int w = 0; w < wid; w++) wpre += ws[w];
  int base = cpre[b] + wpre + incl - s;
  #pragma unroll
  for (int k = 0; k < 4; k++){
    int i = b*CHUNK + tid*4 + k;
    if (i < n) offs[i] = base;
    base += x[k];
  }
}

// scatter src ids into CSR slot order (layer-invariant, built once)
__global__ void k_scatter_src(const int* __restrict__ src, const int* __restrict__ dst,
                              const int* __restrict__ offs, int* __restrict__ cnt,
                              int* __restrict__ srcP, int E){
  int e = blockIdx.x*blockDim.x + threadIdx.x;
  if (e < E){ int d = dst[e]; int p = atomicAdd(&cnt[d], 1); srcP[offs[d] + p] = src[e]; }
}

__global__ void k_graph_bounds(const int* __restrict__ ng, int* __restrict__ gstart, int n, int nb){
  int i = blockIdx.x*blockDim.x + threadIdx.x;
  if (i >= n) return;
  int g = ng[i];
  int gp = (i == 0) ? -1 : ng[i-1];
  for (int b = gp+1; b <= g; b++) gstart[b] = i;
  if (i == n-1) for (int b = g+1; b <= nb; b++) gstart[b] = n;
}

// ---------------- fused nfeats->bf16 + layer-0 pool gate (wave per node) ----------------
__global__ __launch_bounds__(256) void k_tobf16_gate(const float* __restrict__ in,
    const float* __restrict__ gw, const float* __restrict__ gb,
    ushort* __restrict__ out, float* __restrict__ gate, int Nn){
  int n = blockIdx.x*4 + (threadIdx.x >> 6);
  if (n >= Nn) return;
  int lane = threadIdx.x & 63;
  float2 v = *(const float2*)(in + (size_t)n*128 + lane*2);
  unsigned pk = (f2bf_rne(v.y) << 16) | f2bf_rne(v.x);
  *(unsigned*)(out + (size_t)n*128 + lane*2) = pk;
  float2 gv = *(const float2*)(gw + lane*2);
  float p = v.x*gv.x + v.y*gv.y;
  for (int k = 1; k < 64; k <<= 1) p += __shfl_xor(p, k);
  if (lane == 0) gate[n] = p + gb[0];
}

// W [128,256] f32 -> Wt [256,128] bf16
__global__ void k_wt(const float* __restrict__ W, ushort* __restrict__ Wt, int total){
  int idx = blockIdx.x*blockDim.x + threadIdx.x;
  if (idx >= total) return;
  int c = idx >> 7;
  int k = idx & 127;
  Wt[idx] = (ushort)f2bf_rne(W[(size_t)k*256 + c]);
}

// LSTM weight prep: packed bf16 pairs.
__global__ void k_lstm_prep(const float* __restrict__ Wih, const float* __restrict__ Whh,
                            const float* __restrict__ bih, const float* __restrict__ bhh,
                            unsigned* __restrict__ Wxp, unsigned* __restrict__ Whp,
                            float* __restrict__ bias2){
  int idx = blockIdx.x*blockDim.x + threadIdx.x;   // 2*2*64*512 = 131072
  if (idx >= 131072) return;
  int j   = idx & 511;
  int c   = (idx >> 9) & 63;
  int isH = (idx >> 15) & 1;
  int l   = idx >> 16;
  const float* srcW = isH ? Whh : Wih;
  float w0 = srcW[(size_t)l*512*128 + (size_t)j*128 + 2*c];
  float w1 = srcW[(size_t)l*512*128 + (size_t)j*128 + 2*c + 1];
  unsigned v = (f2bf_rne(w1) << 16) | f2bf_rne(w0);
  unsigned* dst = isH ? Whp : Wxp;
  dst[(size_t)l*32768 + c*512 + j] = v;
  if (!isH && c == 0) bias2[l*512 + j] = bih[l*512 + j] + bhh[l*512 + j];
}

// ---------------- MFMA GEMM (Wt staged in LDS): Y8[M,256](fp8) = Xh[M,128] @ W, fused el/er ----------------
// LDS layout [c=0..15][row=0..255][8 ushorts]: quarter-wave reads 16 contiguous rows -> conflict-free.
__global__ __launch_bounds__(256) void k_gemm_mfma(const ushort* __restrict__ Xh,
    const ushort* __restrict__ Wt, const float* __restrict__ alv, const float* __restrict__ arv,
    unsigned char* __restrict__ Y8, float* __restrict__ el, float* __restrict__ er, int M){
  __shared__ ushort WlS[16*256*8];   // 64 KB
  int tid = threadIdx.x;
  #pragma unroll
  for (int i = 0; i < 16; i++){
    int g = i*256 + tid;
    int row = g >> 4, c = g & 15;
    *(uint4*)(WlS + ((size_t)c*256 + row)*8) = *(const uint4*)(Wt + (size_t)row*128 + c*8);
  }
  __syncthreads();
  int wave = tid >> 6;
  int lane = tid & 63;
  int strip = blockIdx.x*4 + wave;
  if (strip*16 >= M) return;
  int m0 = strip*16;
  int l15 = lane & 15;
  int kg  = lane >> 4;
  int arow = m0 + l15; if (arow >= M) arow = M-1;
  short8v a[4];
  const ushort* xrow = Xh + (size_t)arow*128 + kg*8;
  #pragma unroll
  for (int ks = 0; ks < 4; ks++) a[ks] = *(const short8v*)(xrow + ks*32);
  float4v acc[16];
  #pragma unroll
  for (int nt = 0; nt < 16; nt++) acc[nt] = (float4v){0.f,0.f,0.f,0.f};
  #pragma unroll
  for (int nt = 0; nt < 16; nt++){
    #pragma unroll
    for (int ks = 0; ks < 4; ks++){
      short8v b = *(const short8v*)(WlS + (((size_t)(kg + ks*4)*256) + nt*16 + l15)*8);
      acc[nt] = __builtin_amdgcn_mfma_f32_16x16x32_bf16(a[ks], b, acc[nt], 0, 0, 0);
    }
  }
  float pel0[4]={0,0,0,0}, pel1[4]={0,0,0,0}, per0[4]={0,0,0,0}, per1[4]={0,0,0,0};
  #pragma unroll
  for (int nt = 0; nt < 16; nt++){
    int col = nt*16 + l15;
    float av = alv[col], rv = arv[col];
    #pragma unroll
    for (int j = 0; j < 4; j++){
      float v = acc[nt][j];
      int r = m0 + kg*4 + j;
      if (r < M) Y8[(size_t)r*256 + col] = f2fp8(v);
      if (nt < 8){ pel0[j] += v*av; per0[j] += v*rv; }
      else       { pel1[j] += v*av; per1[j] += v*rv; }
    }
  }
  #pragma unroll
  for (int j = 0; j < 4; j++){
    #pragma unroll
    for (int d = 1; d < 16; d <<= 1){
      pel0[j] += __shfl_xor(pel0[j], d);
      pel1[j] += __shfl_xor(pel1[j], d);
      per0[j] += __shfl_xor(per0[j], d);
      per1[j] += __shfl_xor(per1[j], d);
    }
  }
  if (l15 == 0){
    #pragma unroll
    for (int j = 0; j < 4; j++){
      int r = m0 + kg*4 + j;
      if (r < M){
        el[(size_t)r*2+0] = pel0[j];
        el[(size_t)r*2+1] = pel1[j];
        er[(size_t)r*2+0] = per0[j];
        er[(size_t)r*2+1] = per1[j];
      }
    }
  }
}

// ---------------- softmax + aggregate (in-kernel scores, fp8 gather, 4 edges/iter, 16B/lane) ----------------
// Unnormalized exp weights in LDS; 1/sum applied once to the accumulator (per head).
// quarter = lane>>4 picks edge i+quarter; sub = lane&15 covers 16 dims of flat 256 (head = sub>>3).
#define MAXE 256
__global__ __launch_bounds__(256) void k_aggregate(const unsigned char* __restrict__ hpair8,
    const float* __restrict__ el, const float* __restrict__ er,
    const int* __restrict__ srcP, const int* __restrict__ offs,
    const float* __restrict__ bias, const float* __restrict__ gwv, const float* __restrict__ gbv,
    ushort* __restrict__ outh, float* __restrict__ gate, int Nn){
  __shared__ float sw[4][MAXE][2];   // scores -> unnormalized exp weights (8 KB)
  __shared__ int   ss[4][MAXE];      // src ids (4 KB)
  int wave = threadIdx.x >> 6;
  int n = blockIdx.x*4 + wave;
  if (n >= Nn) return;
  int lane = threadIdx.x & 63;
  int e0 = offs[n], e1 = offs[n+1];
  int deg = e1 - e0;
  int quarter = lane >> 4;     // which edge of the 4-pack
  int sub     = lane & 15;     // 16-dim slice of flat 256
  int head    = sub >> 3;
  float2 erv = *(const float2*)(er + (size_t)n*2);
  float2v acc[8];
  #pragma unroll
  for (int k = 0; k < 8; k++) acc[k] = (float2v){0.f, 0.f};
  float inv0, inv1;

  if (deg <= MAXE){
    float m0 = -3.4e38f, m1 = -3.4e38f;
    for (int i = lane; i < deg; i += 64){
      int s = srcP[e0 + i];
      ss[wave][i] = s;
      float2 lv = *(const float2*)(el + (size_t)s*2);
      float v0 = lv.x + erv.x, v1 = lv.y + erv.y;
      v0 = (v0 > 0.f) ? v0 : 0.2f*v0;
      v1 = (v1 > 0.f) ? v1 : 0.2f*v1;
      sw[wave][i][0] = v0; sw[wave][i][1] = v1;
      m0 = fmaxf(m0, v0); m1 = fmaxf(m1, v1);
    }
    for (int k = 1; k < 64; k <<= 1){ m0 = fmaxf(m0, __shfl_xor(m0, k)); m1 = fmaxf(m1, __shfl_xor(m1, k)); }
    // combined: exp + store (unnormalized) + sum
    float s0 = 0.f, s1 = 0.f;
    for (int i = lane; i < deg; i += 64){
      float x0 = fexp(sw[wave][i][0] - m0);
      float x1 = fexp(sw[wave][i][1] - m1);
      sw[wave][i][0] = x0; sw[wave][i][1] = x1;
      s0 += x0; s1 += x1;
    }
    for (int k = 1; k < 64; k <<= 1){ s0 += __shfl_xor(s0, k); s1 += __shfl_xor(s1, k); }
    inv0 = (s0 > 0.f) ? 1.f/s0 : 0.f;
    inv1 = (s1 > 0.f) ? 1.f/s1 : 0.f;
    // gather (wave-internal LDS producer->consumer: no barrier needed)
    for (int i = quarter; i < deg; i += 4){
      int s = ss[wave][i];
      float w = sw[wave][i][head];
      uint4 hv = *(const uint4*)(hpair8 + (size_t)s*256 + sub*16);
      float2v wv = { w, w };
      acc[0] += wv*__builtin_amdgcn_cvt_pk_f32_fp8(hv.x, false);
      acc[1] += wv*__builtin_amdgcn_cvt_pk_f32_fp8(hv.x, true);
      acc[2] += wv*__builtin_amdgcn_cvt_pk_f32_fp8(hv.y, false);
      acc[3] += wv*__builtin_amdgcn_cvt_pk_f32_fp8(hv.y, true);
      acc[4] += wv*__builtin_amdgcn_cvt_pk_f32_fp8(hv.z, false);
      acc[5] += wv*__builtin_amdgcn_cvt_pk_f32_fp8(hv.z, true);
      acc[6] += wv*__builtin_amdgcn_cvt_pk_f32_fp8(hv.w, false);
      acc[7] += wv*__builtin_amdgcn_cvt_pk_f32_fp8(hv.w, true);
    }
  } else {
    // slow path (deg > MAXE): recompute per chunk, unnormalized
    float m0 = -3.4e38f, m1 = -3.4e38f;
    for (int i = e0 + lane; i < e1; i += 64){
      int s = srcP[i];
      float2 lv = *(const float2*)(el + (size_t)s*2);
      float v0 = lv.x + erv.x, v1 = lv.y + erv.y;
      v0 = (v0 > 0.f) ? v0 : 0.2f*v0;
      v1 = (v1 > 0.f) ? v1 : 0.2f*v1;
      m0 = fmaxf(m0, v0); m1 = fmaxf(m1, v1);
    }
    for (int k = 1; k < 64; k <<= 1){ m0 = fmaxf(m0, __shfl_xor(m0, k)); m1 = fmaxf(m1, __shfl_xor(m1, k)); }
    float s0 = 0.f, s1 = 0.f;
    for (int i = e0 + lane; i < e1; i += 64){
      int s = srcP[i];
      float2 lv = *(const float2*)(el + (size_t)s*2);
      float v0 = lv.x + erv.x, v1 = lv.y + erv.y;
      v0 = (v0 > 0.f) ? v0 : 0.2f*v0;
      v1 = (v1 > 0.f) ? v1 : 0.2f*v1;
      s0 += fexp(v0 - m0); s1 += fexp(v1 - m1);
    }
    for (int k = 1; k < 64; k <<= 1){ s0 += __shfl_xor(s0, k); s1 += __shfl_xor(s1, k); }
    inv0 = (s0 > 0.f) ? 1.f/s0 : 0.f;
    inv1 = (s1 > 0.f) ? 1.f/s1 : 0.f;
    for (int c0 = e0; c0 < e1; c0 += 64){
      int ce = e1 - c0; if (ce > 64) ce = 64;
      if (lane < ce){
        int s = srcP[c0 + lane];
        float2 lv = *(const float2*)(el + (size_t)s*2);
        float v0 = lv.x + erv.x, v1 = lv.y + erv.y;
        v0 = (v0 > 0.f) ? v0 : 0.2f*v0;
        v1 = (v1 > 0.f) ? v1 : 0.2f*v1;
        ss[wave][lane] = s;
        sw[wave][lane][0] = fexp(v0 - m0);
        sw[wave][lane][1] = fexp(v1 - m1);
      }
      for (int i = quarter; i < ce; i += 4){
        int s = ss[wave][i];
        float w = sw[wave][i][head];
        uint4 hv = *(const uint4*)(hpair8 + (size_t)s*256 + sub*16);
        float2v wv = { w, w };
        acc[0] += wv*__builtin_amdgcn_cvt_pk_f32_fp8(hv.x, false);
        acc[1] += wv*__builtin_amdgcn_cvt_pk_f32_fp8(hv.x, true);
        acc[2] += wv*__builtin_amdgcn_cvt_pk_f32_fp8(hv.y, false);
        acc[3] += wv*__builtin_amdgcn_cvt_pk_f32_fp8(hv.y, true);
        acc[4] += wv*__builtin_amdgcn_cvt_pk_f32_fp8(hv.z, false);
        acc[5] += wv*__builtin_amdgcn_cvt_pk_f32_fp8(hv.z, true);
        acc[6] += wv*__builtin_amdgcn_cvt_pk_f32_fp8(hv.w, false);
        acc[7] += wv*__builtin_amdgcn_cvt_pk_f32_fp8(hv.w, true);
      }
    }
  }

  // sum the 4 quarter-partials (xor 16/32 preserves sub -> same head), then normalize
  float inv = head ? inv1 : inv0;
  #pragma unroll
  for (int k = 0; k < 8; k++){
    float2v t16, t32;
    t16[0] = __shfl_xor(acc[k][0], 16); t16[1] = __shfl_xor(acc[k][1], 16);
    acc[k] += t16;
    t32[0] = __shfl_xor(acc[k][0], 32); t32[1] = __shfl_xor(acc[k][1], 32);
    acc[k] += t32;
  }
  float t[16];
  #pragma unroll
  for (int k = 0; k < 16; k++)
    t[k] = fmaxf(acc[k>>1][k&1]*inv + bias[sub*16 + k], 0.f);
  float o[16];
  #pragma unroll
  for (int k = 0; k < 16; k++) o[k] = 0.5f*(t[k] + __shfl_xor(t[k], 8));
  if (lane < 8){
    ushort u[16];
    #pragma unroll
    for (int k = 0; k < 16; k++) u[k] = (ushort)f2bf_rne(o[k]);
    *(uint4*)(outh + (size_t)n*128 + sub*16)     = *(uint4*)u;
    *(uint4*)(outh + (size_t)n*128 + sub*16 + 8) = *(uint4*)(u + 8);
    float gp = 0.f;
    #pragma unroll
    for (int k = 0; k < 16; k++) gp += o[k]*gwv[sub*16 + k];
    #pragma unroll
    for (int d = 1; d < 8; d <<= 1) gp += __shfl_xor(gp, d);
    if (sub == 0) gate[n] = gp + gbv[0];
  }
}

// ---------------- pool partial (fused stats) + reduce ----------------
#define POOL_P 32
__global__ __launch_bounds__(128) void k_pool_partial(const ushort* __restrict__ x,
    const float* __restrict__ gate, const int* __restrict__ gstart,
    float* __restrict__ partials){
  int b = blockIdx.x;
  int p = blockIdx.y;
  int n0 = gstart[b], n1 = gstart[b+1];
  int tid = threadIdx.x, lane = tid & 63, wid = tid >> 6;
  __shared__ float red[2];
  float m = -3.4e38f;
  for (int n = n0 + tid; n < n1; n += 128) m = fmaxf(m, gate[n]);
  for (int k = 1; k < 64; k <<= 1) m = fmaxf(m, __shfl_xor(m, k));
  if (lane == 0) red[wid] = m;
  __syncthreads();
  m = fmaxf(red[0], red[1]);
  __syncthreads();
  float s = 0.f;
  for (int n = n0 + tid; n < n1; n += 128) s += __expf(gate[n] - m);
  for (int k = 1; k < 64; k <<= 1) s += __shfl_xor(s, k);
  if (lane == 0) red[wid] = s;
  __syncthreads();
  s = red[0] + red[1];
  float inv = (s > 0.f) ? 1.f/s : 0.f;
  float acc = 0.f;
  for (int n = n0 + p; n < n1; n += POOL_P){
    float w = __expf(gate[n] - m) * inv;
    acc += w * bf2f(x[(size_t)n*128 + tid]);
  }
  partials[((size_t)b*POOL_P + p)*128 + tid] = acc;
}

__global__ __launch_bounds__(128) void k_pool_reduce(const float* __restrict__ partials,
    float* __restrict__ hg){
  int b = blockIdx.x;
  int tid = threadIdx.x;
  float s = 0.f;
  #pragma unroll
  for (int p = 0; p < POOL_P; p++) s += partials[((size_t)b*POOL_P + p)*128 + tid];
  hg[(size_t)b*128 + tid] = s;
}

// ---------------- fused LSTM (2 layers x 4 steps) + final head ----------------
__global__ __launch_bounds__(512) void k_lstm_all(const float* __restrict__ seq,
    const unsigned* __restrict__ Wxp, const unsigned* __restrict__ Whp,
    const float* __restrict__ bias2,
    const float* __restrict__ cw, const float* __restrict__ cb,
    float* __restrict__ out, int B){
  int b = blockIdx.x;
  int j = threadIdx.x;
  __shared__ float xs[4][128];
  __shared__ float gates[512];
  __shared__ float hcur[128], ccur[128];
  __shared__ float l0out[4][128];
  __shared__ float red[2];

  #pragma unroll
  for (int l = 0; l < 2; l++){
    const unsigned* Wx = Wxp + (size_t)l*32768;
    const unsigned* Wh = Whp + (size_t)l*32768;
    const float* bi = bias2 + l*512;
    { int t = j >> 7, k = j & 127;
      xs[t][k] = (l == 0) ? seq[(size_t)t*B*128 + (size_t)b*128 + k] : l0out[t][k];
      if (j < 128){ hcur[j] = 0.f; ccur[j] = 0.f; } }
    __syncthreads();
    float gx[4] = {0.f, 0.f, 0.f, 0.f};
    #pragma unroll 8
    for (int c = 0; c < 64; c++){
      unsigned w2 = Wx[c*512 + j];
      float wlo = __uint_as_float(w2 << 16);
      float whi = __uint_as_float(w2 & 0xffff0000u);
      #pragma unroll
      for (int t = 0; t < 4; t++)
        gx[t] += xs[t][2*c]*wlo + xs[t][2*c+1]*whi;
    }
    #pragma unroll
    for (int t = 0; t < 4; t++){
      float g = gx[t] + bi[j];
      #pragma unroll 8
      for (int c = 0; c < 64; c++){
        unsigned w2 = Wh[c*512 + j];
        g += hcur[2*c]*__uint_as_float(w2 << 16)
           + hcur[2*c+1]*__uint_as_float(w2 & 0xffff0000u);
      }
      gates[j] = g;
      __syncthreads();
      if (j < 128){
        float gi = sigmoidf_(gates[j]);
        float gf = sigmoidf_(gates[128 + j]);
        float gg = tanhf(gates[256 + j]);
        float go = sigmoidf_(gates[384 + j]);
        float c2 = gf * ccur[j] + gi * gg;
        float h = go * tanhf(c2);
        ccur[j] = c2;
        hcur[j] = h;
        if (l == 0) l0out[t][j] = h;
      }
      __syncthreads();
    }
  }
  float p = (j < 128) ? hcur[j] * cw[j] : 0.f;
  if (j < 128){
    for (int k = 1; k < 64; k <<= 1) p += __shfl_xor(p, k);
    if ((j & 63) == 0) red[j >> 6] = p;
  }
  __syncthreads();
  if (j == 0) out[b] = sigmoidf_(red[0] + red[1] + cb[0]);
}

extern "C" void kernel_launch(void* const* d_in, const int* in_sizes, int n_in,
                              void* d_out, int out_size, void* d_ws, size_t ws_size,
                              hipStream_t stream){
  const float* nfeats = (const float*)d_in[0];
  const int*   src    = (const int*)d_in[1];
  const int*   dst    = (const int*)d_in[2];
  const int*   ng     = (const int*)d_in[3];
  const float* Wm[3]  = { (const float*)d_in[4],  (const float*)d_in[8],  (const float*)d_in[12] };
  const float* al[3]  = { (const float*)d_in[5],  (const float*)d_in[9],  (const float*)d_in[13] };
  const float* ar[3]  = { (const float*)d_in[6],  (const float*)d_in[10], (const float*)d_in[14] };
  const float* bb[3]  = { (const float*)d_in[7],  (const float*)d_in[11], (const float*)d_in[15] };
  const float* gw[4]  = { (const float*)d_in[16], (const float*)d_in[18], (const float*)d_in[20], (const float*)d_in[22] };
  const float* gb[4]  = { (const float*)d_in[17], (const float*)d_in[19], (const float*)d_in[21], (const float*)d_in[23] };
  const float* Wih = (const float*)d_in[24];
  const float* Whh = (const float*)d_in[25];
  const float* bih = (const float*)d_in[26];
  const float* bhh = (const float*)d_in[27];
  const float* cw  = (const float*)d_in[28];
  const float* cb  = (const float*)d_in[29];

  const int N = in_sizes[3];      // 50000
  const int E = in_sizes[1];      // 800000
  const int B = out_size;         // 64

  char* p = (char*)d_ws;
  auto alloc = [&](size_t bytes) -> void* {
    void* q = (void*)p;
    p += (bytes + 255) & ~(size_t)255;
    return q;
  };
  unsigned char* hpair8 = (unsigned char*)alloc((size_t)N*256);
  ushort* aggh   = (ushort*)alloc((size_t)N*128*2);
  ushort* xh0    = (ushort*)alloc((size_t)N*128*2);
  ushort* Wt     = (ushort*)alloc((size_t)3*256*128*2);
  float*  el     = (float*)alloc((size_t)N*2*4);
  float*  er     = (float*)alloc((size_t)N*2*4);
  int*    srcP   = (int*)alloc((size_t)E*4);
  float*  gate   = (float*)alloc((size_t)N*4);
  int*    deg    = (int*)alloc((size_t)N*4);
  int*    offs   = (int*)alloc((size_t)(N+1)*4);
  int*    cnt    = (int*)alloc((size_t)N*4);
  int*    gstart = (int*)alloc((size_t)(B+1)*4);
  int*    csum   = (int*)alloc((size_t)64*4);
  int*    cpre   = (int*)alloc((size_t)64*4);
  float*  seqA   = (float*)alloc((size_t)4*B*128*4);
  float*  partials = (float*)alloc((size_t)B*POOL_P*128*4);
  unsigned* Wxp  = (unsigned*)alloc((size_t)2*64*512*4);
  unsigned* Whp  = (unsigned*)alloc((size_t)2*64*512*4);
  float*  bias2  = (float*)alloc((size_t)2*512*4);

  auto cdiv = [](int a, int b){ return (a + b - 1) / b; };
  const int NB = cdiv(N, CHUNK);   // 49 chunks

  hipMemsetAsync(deg, 0, (size_t)N*4, stream);
  hipMemsetAsync(cnt, 0, (size_t)N*4, stream);
  k_hist<<<cdiv(E,256), 256, 0, stream>>>(dst, deg, E);
  k_chunksum<<<NB, 256, 0, stream>>>(deg, csum, N);
  k_scan_small<<<1, 64, 0, stream>>>(csum, cpre, NB, offs + N);
  k_scan_apply<<<NB, 256, 0, stream>>>(deg, cpre, offs, N);
  k_scatter_src<<<cdiv(E,256), 256, 0, stream>>>(src, dst, offs, cnt, srcP, E);
  k_graph_bounds<<<cdiv(N,256), 256, 0, stream>>>(ng, gstart, N, B);

  // conversions + fused layer-0 gate
  k_tobf16_gate<<<cdiv(N,4), 256, 0, stream>>>(nfeats, gw[0], gb[0], xh0, gate, N);
  for (int l = 0; l < 3; l++)
    k_wt<<<cdiv(256*128, 256), 256, 0, stream>>>(Wm[l], Wt + (size_t)l*256*128, 256*128);
  k_lstm_prep<<<cdiv(131072, 256), 256, 0, stream>>>(Wih, Whh, bih, bhh, Wxp, Whp, bias2);

  auto pool_rest = [&](const ushort* xv, float* hgv){
    dim3 pg(B, POOL_P);
    k_pool_partial<<<pg, 128, 0, stream>>>(xv, gate, gstart, partials);
    k_pool_reduce<<<B, 128, 0, stream>>>(partials, hgv);
  };

  // pool 0 on raw features (bf16 copy)
  pool_rest(xh0, seqA + 0*(size_t)B*128);

  const ushort* xh = xh0;
  const int strips = cdiv(N, 16);
  for (int layer = 0; layer < 3; layer++){
    k_gemm_mfma<<<cdiv(strips,4), 256, 0, stream>>>(xh, Wt + (size_t)layer*256*128,
        al[layer], ar[layer], hpair8, el, er, N);
    k_aggregate<<<cdiv(N,4), 256, 0, stream>>>(hpair8, el, er, srcP, offs,
        bb[layer], gw[layer+1], gb[layer+1], aggh, gate, N);
    pool_rest(aggh, seqA + (size_t)(layer+1)*B*128);
    xh = aggh;
  }

  k_lstm_all<<<B, 512, 0, stream>>>(seqA, Wxp, Whp, bias2, cw, cb, (float*)d_out, B);
}